// Round 5
// baseline (386.610 us; speedup 1.0000x reference)
//
#include <hip/hip_runtime.h>

// Attention_76459007804089, fp32: M=8192 graphs x 64 nodes x 128 dims.
// Kernel 1: ha = h @ a  (8192x128 @ 128x128) into d_ws.
// Kernel 2: fused per-graph attention, register-resident x (no LDS x-tile):
//   thread (row i=t>>2, phase qt=t&3) owns dims' float4-chunks {qt+4c} of row i.
//   Per-instr global pattern: 16 x 64B fully-used segments (perfect coalescing).
//   2 barriers, 8.5 KB LDS -> ~6-7 blocks/CU (vs 4 with a 38 KB tile).

#define NPG  64    // nodes per graph (batch_num_nodes uniformly 64)
#define DDIM 128
#define OROW 132   // opart padded row stride (dwords): rotates banks by 4/row

typedef __attribute__((ext_vector_type(4))) float f32x4;

// ---------------- Kernel 1: ha = h @ a ----------------
__global__ __launch_bounds__(256) void ha_gemm_kernel(
    const float* __restrict__ h, const float* __restrict__ a, float* __restrict__ ha)
{
    const int j    = threadIdx.x & 127;
    const int rg   = threadIdx.x >> 7;           // 0,1
    const int row0 = blockIdx.x * 8 + rg * 4;
    const float* hp = h + (size_t)row0 * DDIM;

    float acc0 = 0.f, acc1 = 0.f, acc2 = 0.f, acc3 = 0.f;
    #pragma unroll 8
    for (int k4 = 0; k4 < 32; ++k4) {
        f32x4 h0 = *(const f32x4*)(hp + 0 * DDIM + k4 * 4);   // wave-uniform -> L1 broadcast
        f32x4 h1 = *(const f32x4*)(hp + 1 * DDIM + k4 * 4);
        f32x4 h2 = *(const f32x4*)(hp + 2 * DDIM + k4 * 4);
        f32x4 h3 = *(const f32x4*)(hp + 3 * DDIM + k4 * 4);
        #pragma unroll
        for (int kk = 0; kk < 4; ++kk) {
            float av = a[(k4 * 4 + kk) * DDIM + j];           // lane-coalesced, L2-resident
            acc0 += h0[kk] * av;
            acc1 += h1[kk] * av;
            acc2 += h2[kk] * av;
            acc3 += h3[kk] * av;
        }
    }
    float* op = ha + (size_t)row0 * DDIM + j;
    op[0 * DDIM] = acc0; op[1 * DDIM] = acc1; op[2 * DDIM] = acc2; op[3 * DDIM] = acc3;
}

// ---------------- Kernel 2: fused attention, x in registers ----------------
__global__ __launch_bounds__(256, 6) void attn_kernel(
    const float* __restrict__ x, const float* __restrict__ ha, float* __restrict__ out)
{
    const int g  = blockIdx.x;
    const int t  = threadIdx.x;
    const int w  = t >> 6;        // wave 0..3
    const int l  = t & 63;        // lane
    const int i  = t >> 2;        // node/row 0..63  (= 16*w + (l>>2))
    const int qt = t & 3;         // dim phase: this thread owns float4-chunks {qt+4c}

    __shared__ float zbuf[4];
    __shared__ __align__(16) float opart[16][OROW];   // 16 row-block partials, padded

    // Load x slice (32 dims) + matching q chunks; x stays in VGPRs for phase D.
    const float* xrow = x  + ((size_t)g * NPG + i) * DDIM;
    const float* qrow = ha + (size_t)g * DDIM;
    f32x4 xv[8];
    #pragma unroll
    for (int c = 0; c < 8; ++c)
        xv[c] = *(const f32x4*)(xrow + (qt + 4 * c) * 4);

    float e = 0.f;
    #pragma unroll
    for (int c = 0; c < 8; ++c) {
        f32x4 qv = *(const f32x4*)(qrow + (qt + 4 * c) * 4);  // 4 addrs/wave -> L1/L2 broadcast
        e += xv[c][0] * qv[0] + xv[c][1] * qv[1] + xv[c][2] * qv[2] + xv[c][3] * qv[3];
    }
    // Combine the 4 qt-phases of this row -> full e_i on all 4 lanes of the group.
    e += __shfl_xor(e, 1, 64);
    e += __shfl_xor(e, 2, 64);
    float ex = __expf(e);         // unstabilized exp, faithful to reference

    // Wave z partial: xor-4..32 sums the wave's 16 distinct rows (ex uniform per group).
    float zw = ex;
    zw += __shfl_xor(zw, 4, 64);
    zw += __shfl_xor(zw, 8, 64);
    zw += __shfl_xor(zw, 16, 64);
    zw += __shfl_xor(zw, 32, 64);
    if (l == 0) zbuf[w] = zw;
    __syncthreads();

    const float rz  = 1.0f / (zbuf[0] + zbuf[1] + zbuf[2] + zbuf[3]);
    const float att = ex * rz;

    // Phase D: scale rows in-register, butterfly 2 stages (rows i^1, i^2-pairs)
    #pragma unroll
    for (int c = 0; c < 8; ++c) {
        xv[c][0] *= att; xv[c][1] *= att; xv[c][2] *= att; xv[c][3] *= att;
    }
    #pragma unroll
    for (int c = 0; c < 8; ++c) {
        #pragma unroll
        for (int u = 0; u < 4; ++u) {
            xv[c][u] += __shfl_xor(xv[c][u], 4, 64);   // + row i^1
            xv[c][u] += __shfl_xor(xv[c][u], 8, 64);   // + rows (i^2 pair)
        }
    }
    // Lanes with (l>>2)&3 == 0 hold the 4-row block sum; block id = w*4 + (l>>4).
    if (((l >> 2) & 3) == 0) {
        const int blk = w * 4 + (l >> 4);
        #pragma unroll
        for (int c = 0; c < 8; ++c)
            *(f32x4*)(&opart[blk][(qt + 4 * c) * 4]) = xv[c];
    }
    __syncthreads();

    // Final: 128 threads sum the 16 block partials for their dim.
    if (t < DDIM) {
        float o = 0.f;
        #pragma unroll
        for (int p = 0; p < 16; ++p) o += opart[p][t];   // stride-132 rows: 2-way, free
        out[(size_t)g * DDIM + t] = o;
    }
}

extern "C" void kernel_launch(void* const* d_in, const int* in_sizes, int n_in,
                              void* d_out, int out_size, void* d_ws, size_t ws_size,
                              hipStream_t stream) {
    const float* h = (const float*)d_in[0];   // (M, 128) fp32
    const float* x = (const float*)d_in[1];   // (N, 128) fp32
    const float* a = (const float*)d_in[2];   // (128, 128) fp32
    // d_in[3] = batch_num_nodes (int32): uniformly 64 -> node n belongs to graph n/64
    float* out = (float*)d_out;               // (M, 128) fp32
    float* ha  = (float*)d_ws;                // (M, 128) fp32 scratch, rewritten every call

    const int m = in_sizes[0] / DDIM;         // 8192 graphs
    ha_gemm_kernel<<<m / 8, 256, 0, stream>>>(h, a, ha);
    attn_kernel<<<m, 256, 0, stream>>>(x, ha, out);
}